// Round 1
// baseline (5586.451 us; speedup 1.0000x reference)
//
#include <hip/hip_runtime.h>
#include <stdint.h>

// PeepholeLSTM (actually standard LSTM): B=128, T=512, I=256, H=512.
// Strategy: 8 groups (16 batches each) x 32 WGs (16 h-cols each) = 256 WGs, 1/CU.
// Weights [W|U] resident in VGPRs as MFMA B-frags (K-partitioned over 4 waves).
// Per step: MFMA (M=16 batches, N=64 gate-outputs, K=768), LDS reduce over waves,
// elementwise update, h broadcast via agent-scope atomics in d_ws, group barrier.

#define B_ 128
#define T_ 512
#define I_ 256
#define H_ 512
#define NWG 32   // workgroups per group
#define NB 16    // batches per group

using short8 = __attribute__((ext_vector_type(8))) short;
using f32x4  = __attribute__((ext_vector_type(4))) float;

union V16 {
  uint32_t u[4];
  short8 s;
};

__device__ __forceinline__ unsigned short bf16rne(float f) {
  uint32_t u = __builtin_bit_cast(uint32_t, f);
  u += 0x7fffu + ((u >> 16) & 1u);
  return (unsigned short)(u >> 16);
}

__device__ __forceinline__ short8 cvt8(float4 a, float4 b) {
  short8 r;
  r[0] = (short)bf16rne(a.x); r[1] = (short)bf16rne(a.y);
  r[2] = (short)bf16rne(a.z); r[3] = (short)bf16rne(a.w);
  r[4] = (short)bf16rne(b.x); r[5] = (short)bf16rne(b.y);
  r[6] = (short)bf16rne(b.z); r[7] = (short)bf16rne(b.w);
  return r;
}

__global__ __launch_bounds__(256, 1) void lstm_fused(
    const float* __restrict__ x,
    const float* __restrict__ Wi, const float* __restrict__ Ui, const float* __restrict__ bi,
    const float* __restrict__ Wf, const float* __restrict__ Uf, const float* __restrict__ bfv,
    const float* __restrict__ Wo, const float* __restrict__ Uo, const float* __restrict__ bo,
    const float* __restrict__ Wc, const float* __restrict__ Uc, const float* __restrict__ bc,
    float* __restrict__ out, uint32_t* __restrict__ ws)
{
  const int bid   = blockIdx.x;
  const int group = bid & 7;        // XCD-locality heuristic only (not correctness)
  const int wg    = bid >> 3;       // 0..31 within group
  const int tid   = threadIdx.x;
  const int lane  = tid & 63;
  const int wave  = tid >> 6;       // 0..3
  const int quad  = lane >> 4;      // 0..3
  const int row16 = lane & 15;      // A: batch row / B: output col / C: col
  const int bg0   = group * NB;     // first batch of group
  const int col0  = wg * 16;        // first h-column of this WG

  uint32_t* ctr  = ws + group * 64;   // one arrive-counter per group (cacheline spaced)
  uint32_t* hbuf = ws + 1024;         // [2][128][256] dwords of packed bf16 h

  __shared__ float part[16 * 256];    // [wave][gate][n=16][m=16]

  const float* Wg[4] = {Wi, Wf, Wo, Wc};
  const float* Ug[4] = {Ui, Uf, Uo, Uc};

  // ---- load resident B (weight) fragments: wave covers K in [wave*192, wave*192+192) ----
  // B-frag for 16x16x32: lane holds B[k = quad*8+j][n = lane&15]; weights are [n][k] row-major.
  short8 bfr[6][4];
  const int kbase = wave * 192;
  #pragma unroll
  for (int ki = 0; ki < 6; ++ki) {
    const int kk = kbase + ki * 32;
    const int k  = kk + quad * 8;
    #pragma unroll
    for (int g = 0; g < 4; ++g) {
      const float* src = (kk < 512)
        ? (Wg[g] + (size_t)(col0 + row16) * H_ + k)
        : (Ug[g] + (size_t)(col0 + row16) * I_ + (k - 512));
      float4 lo = *(const float4*)src;
      float4 hi = *(const float4*)(src + 4);
      bfr[ki][g] = cvt8(lo, hi);
    }
  }

  // ---- update-phase constants: thread (ub=batch, uc=col) ----
  const int ub = tid >> 4;
  const int uc = tid & 15;
  const float* bptr[4] = {bi, bfv, bo, bc};
  float bias[4];
  #pragma unroll
  for (int g = 0; g < 4; ++g) bias[g] = bptr[g][col0 + uc];

  float c_reg = 0.0f;

  for (int t = 0; t < T_; ++t) {
    if (t > 0) {
      if (tid == 0) {
        while (__hip_atomic_load(ctr, __ATOMIC_ACQUIRE, __HIP_MEMORY_SCOPE_AGENT)
               < (uint32_t)(NWG * t))
          __builtin_amdgcn_s_sleep(1);
      }
      __syncthreads();
    }

    // ---- gather A fragments (issue all loads before MFMA consumption) ----
    // A-frag: lane holds A[m = lane&15][k = quad*8+j].
    uint32_t araw[6][4];
    #pragma unroll
    for (int ki = 0; ki < 6; ++ki) {
      const int kk = kbase + ki * 32;
      const int k  = kk + quad * 8;
      if (kk < 512) {
        if (t > 0) {
          const uint32_t base = (uint32_t)(t & 1) * 32768u
                              + (uint32_t)(bg0 + row16) * 256u + (uint32_t)(k >> 1);
          #pragma unroll
          for (int d = 0; d < 4; ++d)
            araw[ki][d] = __hip_atomic_load(hbuf + base + d,
                                            __ATOMIC_RELAXED, __HIP_MEMORY_SCOPE_AGENT);
        } else {
          araw[ki][0] = araw[ki][1] = araw[ki][2] = araw[ki][3] = 0u;
        }
      } else {
        const float* xp = x + ((size_t)(bg0 + row16) * T_ + t) * I_ + (k - 512);
        float4 lo = *(const float4*)xp;
        float4 hi = *(const float4*)(xp + 4);
        V16 v; v.s = cvt8(lo, hi);
        araw[ki][0] = v.u[0]; araw[ki][1] = v.u[1];
        araw[ki][2] = v.u[2]; araw[ki][3] = v.u[3];
      }
    }

    // ---- MFMA: 6 K-iters x 4 gates, 4 independent accumulator chains ----
    f32x4 acc[4] = {{0.f,0.f,0.f,0.f},{0.f,0.f,0.f,0.f},
                    {0.f,0.f,0.f,0.f},{0.f,0.f,0.f,0.f}};
    #pragma unroll
    for (int ki = 0; ki < 6; ++ki) {
      V16 v;
      v.u[0] = araw[ki][0]; v.u[1] = araw[ki][1];
      v.u[2] = araw[ki][2]; v.u[3] = araw[ki][3];
      short8 a = v.s;
      #pragma unroll
      for (int g = 0; g < 4; ++g)
        acc[g] = __builtin_amdgcn_mfma_f32_16x16x32_bf16(a, bfr[ki][g], acc[g], 0, 0, 0);
    }

    // ---- write partials to LDS: [wave][gate][n][m], b128 per gate ----
    // C/D layout: col(n) = lane&15, row(m) = quad*4 + reg.
    #pragma unroll
    for (int g = 0; g < 4; ++g)
      *(f32x4*)&part[((wave * 4 + g) << 8) + (row16 << 4) + (quad << 2)] = acc[g];
    __syncthreads();

    // ---- elementwise update: one thread per (batch, col) ----
    float pre[4];
    #pragma unroll
    for (int g = 0; g < 4; ++g) {
      float s = bias[g];
      #pragma unroll
      for (int w = 0; w < 4; ++w)
        s += part[((w * 4 + g) << 8) + (uc << 4) + ub];
      pre[g] = s;
    }
    const float ig = 1.0f / (1.0f + __expf(-pre[0]));
    const float fg = 1.0f / (1.0f + __expf(-pre[1]));
    const float og = 1.0f / (1.0f + __expf(-pre[2]));
    const float e2  = __expf(2.0f * pre[3]);
    const float ct  = (e2 - 1.0f) / (e2 + 1.0f);
    c_reg = fg * c_reg + ig * ct;
    const float e2c = __expf(2.0f * c_reg);
    const float tc  = (e2c - 1.0f) / (e2c + 1.0f);
    const float h   = og * tc;

    out[((size_t)(bg0 + ub) * T_ + t) * H_ + (col0 + uc)] = h;

    if (t == T_ - 1) {
      // h_T
      out[(size_t)B_ * T_ * H_ + (size_t)(bg0 + ub) * H_ + (col0 + uc)] = h;
    } else {
      // publish h_{t+1} as packed bf16 pairs (even col: low half)
      const float hpart = __shfl_xor(h, 1);
      if ((uc & 1) == 0) {
        const uint32_t v = (uint32_t)bf16rne(h) | ((uint32_t)bf16rne(hpart) << 16);
        const uint32_t idx = (uint32_t)((t + 1) & 1) * 32768u
                           + (uint32_t)(bg0 + ub) * 256u
                           + (uint32_t)((col0 + uc) >> 1);
        __hip_atomic_store(hbuf + idx, v, __ATOMIC_RELAXED, __HIP_MEMORY_SCOPE_AGENT);
      }
      __syncthreads();   // all threads' h stores program-ordered before the arrive
      if (tid == 0)
        __hip_atomic_fetch_add(ctr, 1u, __ATOMIC_RELEASE, __HIP_MEMORY_SCOPE_AGENT);
    }
  }

  // c_T
  out[(size_t)B_ * T_ * H_ + (size_t)B_ * H_ + (size_t)(bg0 + ub) * H_ + (col0 + uc)] = c_reg;
}

extern "C" void kernel_launch(void* const* d_in, const int* in_sizes, int n_in,
                              void* d_out, int out_size, void* d_ws, size_t ws_size,
                              hipStream_t stream) {
  // ws layout: [0,4KB): group arrive-counters (zeroed each launch)
  //            [4KB, 4KB+256KB): double-buffered packed-bf16 h exchange
  hipMemsetAsync(d_ws, 0, 4096, stream);
  dim3 grid(256), block(256);
  lstm_fused<<<grid, block, 0, stream>>>(
      (const float*)d_in[0],
      (const float*)d_in[1], (const float*)d_in[2], (const float*)d_in[3],
      (const float*)d_in[4], (const float*)d_in[5], (const float*)d_in[6],
      (const float*)d_in[7], (const float*)d_in[8], (const float*)d_in[9],
      (const float*)d_in[10], (const float*)d_in[11], (const float*)d_in[12],
      (float*)d_out, (uint32_t*)d_ws);
}